// Round 8
// baseline (406.750 us; speedup 1.0000x reference)
//
#include <hip/hip_runtime.h>
#include <math.h>

#define Bb   32
#define SQ   257
#define SQV  320       // padded vt row stride (covers kt*64..+63 reads)
#define Dm   1024
#define HD   64
#define Ee   8
#define Rr   16
#define GHh  256
#define NT   (Bb*SQ)   // 8224
#define KX   1152      // 1024 + E*R extension
#define LDP  72        // padded LDS row (64 ush + 8) — attn only

typedef unsigned short ush;
typedef _Float16 h16;
typedef __attribute__((ext_vector_type(8))) _Float16 half8;
typedef __attribute__((ext_vector_type(4))) _Float16 half4;
typedef __attribute__((ext_vector_type(8))) short short8;
typedef __attribute__((ext_vector_type(4))) float floatx4;
typedef __attribute__((ext_vector_type(16))) float floatx16;

__device__ __forceinline__ ush f2h(float f) {
    union { h16 h; ush u; } a; a.h = (h16)f; return a.u;
}
__device__ __forceinline__ void store_h4(ush* p, float4 v) {
    half4 h; h.x = (h16)v.x; h.y = (h16)v.y; h.z = (h16)v.z; h.w = (h16)v.w;
    *(half4*)p = h;
}
__device__ __forceinline__ void load16(const ush* g, ush* l) {
    __builtin_amdgcn_global_load_lds(
        (const __attribute__((address_space(1))) unsigned int*)g,
        (__attribute__((address_space(3))) unsigned int*)l,
        16, 0, 0);
}

// ---------------- prep: pool+conv (blocks 0..511) | W/U/V conv (rest) -------
__global__ __launch_bounds__(256) void prep_kernel(
    const float* __restrict__ x, float* __restrict__ pp, ush* __restrict__ xf,
    const float* __restrict__ W0, const float* __restrict__ U0,
    const float* __restrict__ W1, const float* __restrict__ U1,
    const float* __restrict__ W2, const float* __restrict__ U2,
    const float* __restrict__ W3, const float* __restrict__ U3,
    const float* __restrict__ V0, const float* __restrict__ V1,
    const float* __restrict__ V2, const float* __restrict__ V3,
    ush* __restrict__ Bf0, ush* __restrict__ Bf1,
    ush* __restrict__ Bf2, ush* __restrict__ Bf3,
    ush* __restrict__ Vf)
{
    const int bid = blockIdx.x, t = threadIdx.x;
    if (bid < 512) {
        const int c = bid & 15, b = bid >> 4;
        const int s0 = c * 16, s1 = (c == 15) ? SQ : s0 + 16;
        float4 acc = make_float4(0.f, 0.f, 0.f, 0.f);
        const float* xp = x + ((size_t)b * SQ + s0) * Dm + t * 4;
        ush* xo = xf + ((size_t)b * SQ + s0) * Dm + t * 4;
        for (int s = s0; s < s1; ++s, xp += Dm, xo += Dm) {
            float4 v = *(const float4*)xp;
            store_h4(xo, v);
            acc.x += v.x; acc.y += v.y; acc.z += v.z; acc.w += v.w;
        }
        *(float4*)(pp + ((size_t)b * 16 + c) * Dm + t * 4) = acc;
        return;
    }
    const int bx = bid - 512;
    const int p = bx / 1280, xb = bx % 1280;
    if (xb < 1152) {
        const float* W = p == 0 ? W0 : p == 1 ? W1 : p == 2 ? W2 : W3;
        const float* U = p == 0 ? U0 : p == 1 ? U1 : p == 2 ? U2 : U3;
        ush* Bf = p == 0 ? Bf0 : p == 1 ? Bf1 : p == 2 ? Bf2 : Bf3;
        const int i = xb * 256 + t;
        const int n = i / 288, c4 = i % 288, col = c4 * 4;
        float4 v;
        if (col < Dm) {
            v = *(const float4*)(W + (size_t)n * Dm + col);
        } else {
            int ec = col - Dm, e = ec >> 4, r = ec & 15;
            v = *(const float4*)(U + ((size_t)(e * Dm + n)) * Rr + r);
        }
        store_h4(Bf + (size_t)n * KX + col, v);
    } else {
        const float* V = p == 0 ? V0 : p == 1 ? V1 : p == 2 ? V2 : V3;
        const size_t i = ((size_t)(xb - 1152) * 256 + t) * 4;
        float4 v = *(const float4*)(V + i);
        store_h4(Vf + (size_t)p * Ee * Rr * Dm + i, v);
    }
}

// ----------------------------------------------- gating stage B: MLP + top2 -
__global__ __launch_bounds__(256) void gating2_kernel(
    const float* __restrict__ pp, const float* __restrict__ gw1,
    const float* __restrict__ gb1, const float* __restrict__ gw2,
    const float* __restrict__ gb2,
    float* __restrict__ gates, int* __restrict__ idx)
{
    __shared__ float pooled[Dm];
    __shared__ float hbuf[GHh];
    __shared__ float logits[Ee];
    const int b = blockIdx.x, t = threadIdx.x;
    const int w = t >> 6, lane = t & 63;

    float4 acc = make_float4(0.f, 0.f, 0.f, 0.f);
    for (int c = 0; c < 16; ++c) {
        float4 v = *(const float4*)(pp + ((size_t)b * 16 + c) * Dm + t * 4);
        acc.x += v.x; acc.y += v.y; acc.z += v.z; acc.w += v.w;
    }
    const float sc = 1.0f / SQ;
    pooled[t*4+0] = acc.x * sc; pooled[t*4+1] = acc.y * sc;
    pooled[t*4+2] = acc.z * sc; pooled[t*4+3] = acc.w * sc;
    __syncthreads();

    for (int oi = 0; oi < 64; ++oi) {
        const int o = w * 64 + oi;
        const float* g = gw1 + (size_t)o * Dm;
        float s = 0.f;
        #pragma unroll
        for (int i = 0; i < 16; ++i) s += pooled[lane + i*64] * g[lane + i*64];
        for (int off = 32; off > 0; off >>= 1) s += __shfl_down(s, off, 64);
        if (lane == 0) hbuf[o] = fmaxf(s + gb1[o], 0.f);
    }
    __syncthreads();
    if (t < Ee) {
        const float* g = gw2 + t * GHh;
        float s = 0.f;
        for (int j = 0; j < GHh; ++j) s += hbuf[j] * g[j];
        logits[t] = s + gb2[t];
    }
    __syncthreads();
    if (t == 0) {
        int i1 = 0; float v1 = logits[0];
        for (int e = 1; e < Ee; ++e) if (logits[e] > v1) { v1 = logits[e]; i1 = e; }
        int i2 = 0; float v2 = -1e30f;
        for (int e = 0; e < Ee; ++e) if (e != i1 && logits[e] > v2) { v2 = logits[e]; i2 = e; }
        float e2 = __expf(v2 - v1);
        float inv = 1.f / (1.f + e2);
        gates[b*2+0] = inv; gates[b*2+1] = e2 * inv;
        idx[b*2+0] = i1; idx[b*2+1] = i2;
    }
}

// --------------- ext as MFMA GEMM: xvs[s,j] = gS * (x[s,:] . Vsel[j,:]) -----
// grid (5 m-tiles, Bb, 2 experts). BK=64. kk==0 blocks zero the 6 non-selected
// expert slices (replaces the old zero_kernel launch).
template<int NP>
__global__ __launch_bounds__(256) void ext_gemm(
    const ush* __restrict__ xf,
    const ush* __restrict__ Vf,                               // [4][128][1024]
    const float* __restrict__ S0, const float* __restrict__ S1,
    const float* __restrict__ S2,
    ush* __restrict__ o0, ush* __restrict__ o1, ush* __restrict__ o2,
    const float* __restrict__ gates, const int* __restrict__ idx, int pbase)
{
    __shared__ ush sA[2*64*32], sB[2*NP*16*32];
    const int mt = blockIdx.x, b = blockIdx.y, kk = blockIdx.z;
    const int t = threadIdx.x, lane = t & 63, w = t >> 6;
    const int quad = lane >> 4, l16 = lane & 15;
    const int s0 = mt * 64;
    const int e = idx[b*2+kk];
    const float g = gates[b*2+kk];

    if (kk == 0) {
        const int e0 = idx[b*2+0], e1 = idx[b*2+1];
        int zexp[6]; int nz = 0;
        #pragma unroll
        for (int ez = 0; ez < Ee; ++ez)
            if (ez != e0 && ez != e1) zexp[nz++] = ez;
        short8 zv = {0,0,0,0,0,0,0,0};
        for (int u = t; u < NP*64*6; u += 256) {
            const int ei = u % 6; int rest = u / 6;
            const int r64 = rest & 63; const int p = rest >> 6;
            const int s = s0 + r64;
            if (s < SQ) {
                ush* oo = p == 0 ? o0 : p == 1 ? o1 : o2;
                ush* dst = oo + ((size_t)(b*SQ + s)) * 128 + zexp[ei]*16;
                *(short8*)dst = zv;
                *(short8*)(dst + 8) = zv;
            }
        }
    }

    const int rl = lane >> 2;
    const int swsrc = ((lane & 3) ^ ((lane >> 3) & 3)) * 8;  // staging chunk
    const int swrd  = ((quad ^ ((l16 >> 1) & 3)) * 8);       // read chunk

    int sa = s0 + w * 16 + rl; if (sa > SQ - 1) sa = SQ - 1;
    const ush* aptr = xf + ((size_t)(b * SQ + sa)) * Dm + swsrc;
    const ush* bptr = (w < NP)
        ? Vf + ((size_t)(pbase + w)) * Ee * Rr * Dm + ((size_t)(e * Rr + rl)) * Dm + swsrc
        : nullptr;
    ush* la0 = &sA[w * 512];
    ush* la1 = &sA[2048 + w * 512];
    ush* lb0 = (w < NP) ? &sB[w * 512] : nullptr;
    ush* lb1 = (w < NP) ? &sB[NP*512 + w * 512] : nullptr;

    floatx4 S[NP] = {};

    for (int it = 0; it < 16; ++it) {
        __syncthreads();
        load16(aptr, la0); load16(aptr + 32, la1); aptr += 64;
        if (w < NP) {
            load16(bptr, lb0); load16(bptr + 32, lb1); bptr += 64;
        }
        __syncthreads();
        #pragma unroll
        for (int j = 0; j < 2; ++j) {
            const half8 a = *(const half8*)&sA[j*2048 + (w*16 + l16)*32 + swrd];
            #pragma unroll
            for (int p = 0; p < NP; ++p) {
                const half8 bb = *(const half8*)&sB[j*NP*512 + (p*16 + l16)*32 + swrd];
                S[p] = __builtin_amdgcn_mfma_f32_16x16x32_f16(a, bb, S[p], 0, 0, 0);
            }
        }
    }

    #pragma unroll
    for (int p = 0; p < NP; ++p) {
        const float* Sp = p == 0 ? S0 : p == 1 ? S1 : S2;
        const float scale = g * Sp[e * Rr + l16];
        ush* oo = p == 0 ? o0 : p == 1 ? o1 : o2;
        #pragma unroll
        for (int r = 0; r < 4; ++r) {
            const int s = s0 + w * 16 + quad * 4 + r;
            if (s < SQ)
                oo[((size_t)(b * SQ + s)) * 128 + e * 16 + l16] = f2h(S[p][r] * scale);
        }
    }
}

// ------------- f16 MFMA GEMM (32x32x16), K=1152 (1024+ext), BK=64 -----------
template<int MODE>
__global__ __launch_bounds__(256) void gemm_mfma(
    const ush* __restrict__ A,
    const ush* __restrict__ E0, const ush* __restrict__ E1, const ush* __restrict__ E2,
    const ush* __restrict__ B0, const ush* __restrict__ B1, const ush* __restrict__ B2,
    const float* __restrict__ b0, const float* __restrict__ b1, const float* __restrict__ b2,
    ush* __restrict__ y0, ush* __restrict__ y1, ush* __restrict__ vt,
    float* __restrict__ yo, float qscale)
{
    const int stripe = blockIdx.x % 72;
    if (stripe >= 65) return;
    const int nb = blockIdx.x / 72;
    const int z = blockIdx.z;
    const ush* E = z == 0 ? E0 : z == 1 ? E1 : E2;
    const ush* Bm = z == 0 ? B0 : z == 1 ? B1 : B2;
    const float* bias = z == 0 ? b0 : z == 1 ? b1 : b2;

    __shared__ ush sLDS[2*128*64];      // sA | sB ; reused as C-repack (128x128)
    ush* sA = sLDS;
    ush* sB = sLDS + 128*64;
    const int t = threadIdx.x, lane = t & 63, w = t >> 6;
    const int m0 = stripe * 128, n0 = nb * 128;
    const int row8 = lane >> 3, c8l = lane & 7;
    const int swk = (c8l ^ row8) * 8;
    const int wm = w >> 1, wn = w & 1;
    const int l31 = lane & 31, h5 = lane >> 5;

    const ush* ap[4]; const ush* ep[4]; const ush* bp[4];
    ush *la[4], *lb[4];
    #pragma unroll
    for (int c = 0; c < 4; ++c) {
        const int j = c * 4 + w;
        const int rowl = j * 8 + row8;
        int rga = m0 + rowl; if (rga > NT - 1) rga = NT - 1;
        ap[c] = A + (size_t)rga * Dm + swk;
        ep[c] = E + (size_t)rga * 128 + swk;
        bp[c] = Bm + (size_t)(n0 + rowl) * KX + swk;
        la[c] = &sA[j * 512];
        lb[c] = &sB[j * 512];
    }

    int aofs[4][2], bofs[4][2];
    #pragma unroll
    for (int s = 0; s < 4; ++s)
        #pragma unroll
        for (int i = 0; i < 2; ++i) {
            const int g = s * 2 + h5;
            aofs[s][i] = (wm*64 + i*32 + l31) * 64 + ((g ^ (l31 & 7)) * 8);
            bofs[s][i] = (wn*64 + i*32 + l31) * 64 + ((g ^ (l31 & 7)) * 8);
        }

    floatx16 acc[2][2] = {};

    for (int it = 0; it < 16; ++it) {       // main K: xf columns 0..1023
        __syncthreads();
        #pragma unroll
        for (int c = 0; c < 4; ++c) {
            load16(ap[c], la[c]); ap[c] += 64;
            load16(bp[c], lb[c]); bp[c] += 64;
        }
        __syncthreads();
        #pragma unroll
        for (int s = 0; s < 4; ++s) {
            half8 af0 = *(const half8*)&sA[aofs[s][0]];
            half8 af1 = *(const half8*)&sA[aofs[s][1]];
            half8 bf0 = *(const half8*)&sB[bofs[s][0]];
            half8 bf1 = *(const half8*)&sB[bofs[s][1]];
            acc[0][0] = __builtin_amdgcn_mfma_f32_32x32x16_f16(af0, bf0, acc[0][0], 0, 0, 0);
            acc[0][1] = __builtin_amdgcn_mfma_f32_32x32x16_f16(af0, bf1, acc[0][1], 0, 0, 0);
            acc[1][0] = __builtin_amdgcn_mfma_f32_32x32x16_f16(af1, bf0, acc[1][0], 0, 0, 0);
            acc[1][1] = __builtin_amdgcn_mfma_f32_32x32x16_f16(af1, bf1, acc[1][1], 0, 0, 0);
        }
    }
    for (int it = 0; it < 2; ++it) {        // ext K: E columns 0..127
        __syncthreads();
        #pragma unroll
        for (int c = 0; c < 4; ++c) {
            load16(ep[c], la[c]); ep[c] += 64;
            load16(bp[c], lb[c]); bp[c] += 64;
        }
        __syncthreads();
        #pragma unroll
        for (int s = 0; s < 4; ++s) {
            half8 af0 = *(const half8*)&sA[aofs[s][0]];
            half8 af1 = *(const half8*)&sA[aofs[s][1]];
            half8 bf0 = *(const half8*)&sB[bofs[s][0]];
            half8 bf1 = *(const half8*)&sB[bofs[s][1]];
            acc[0][0] = __builtin_amdgcn_mfma_f32_32x32x16_f16(af0, bf0, acc[0][0], 0, 0, 0);
            acc[0][1] = __builtin_amdgcn_mfma_f32_32x32x16_f16(af0, bf1, acc[0][1], 0, 0, 0);
            acc[1][0] = __builtin_amdgcn_mfma_f32_32x32x16_f16(af1, bf0, acc[1][0], 0, 0, 0);
            acc[1][1] = __builtin_amdgcn_mfma_f32_32x32x16_f16(af1, bf1, acc[1][1], 0, 0, 0);
        }
    }

    // ---- epilogue: 32x32 C layout: col=lane&31, row=(r&3)+8*(r>>2)+4*(lane>>5)
    if (MODE == 1) {
        #pragma unroll
        for (int mi = 0; mi < 2; ++mi) {
            #pragma unroll
            for (int ni = 0; ni < 2; ++ni) {
                const int col = n0 + wn*64 + ni*32 + l31;
                const float bsv = bias[col];
                const int rb = m0 + wm*64 + mi*32 + 4*h5;
                #pragma unroll
                for (int r = 0; r < 16; ++r) {
                    const int row = rb + (r & 3) + 8 * (r >> 2);
                    if (row < NT)
                        yo[(size_t)row * Dm + col] = acc[mi][ni][r] + bsv;
                }
            }
        }
    } else {
        __syncthreads();     // all waves done with sA/sB reads
        #pragma unroll
        for (int mi = 0; mi < 2; ++mi) {
            #pragma unroll
            for (int ni = 0; ni < 2; ++ni) {
                const int colL = wn*64 + ni*32 + l31;
                const float bsv = bias[n0 + colL];
                const int rbL = wm*64 + mi*32 + 4*h5;
                #pragma unroll
                for (int r = 0; r < 16; ++r) {
                    const int rowL = rbL + (r & 3) + 8 * (r >> 2);
                    float val = acc[mi][ni][r] + bsv;
                    if (z == 0) val *= qscale;
                    sLDS[rowL*128 + ((((colL>>3) ^ (rowL&7)) << 3) | (colL & 7))] = f2h(val);
                }
            }
        }
        __syncthreads();
        if (z != 2) {
            ush* y = (z == 0) ? y0 : y1;
            #pragma unroll
            for (int i = 0; i < 8; ++i) {
                const int u = i*256 + t;
                const int rowL = u >> 4, cj = u & 15;
                const int row = m0 + rowL;
                if (row < NT) {
                    half8 v = *(const half8*)&sLDS[rowL*128 + ((cj ^ (rowL&7)) << 3)];
                    *(half8*)(y + (size_t)row * Dm + n0 + cj*8) = v;
                }
            }
        } else {
            #pragma unroll
            for (int i = 0; i < 8; ++i) {
                const int u = i*256 + t;
                const int oct = u & 15, colL = u >> 4;
                const int colg = n0 + colL;
                const int h_ = colg >> 6, d_ = colg & 63;
                const size_t vrow = (size_t)h_ * 64 + d_;
                #pragma unroll
                for (int jj = 0; jj < 8; ++jj) {
                    const int rowL = oct + jj*16;
                    const int row = m0 + rowL;
                    if (row < NT) {
                        const int b_ = row / SQ, s_ = row - b_*SQ;
                        vt[((size_t)b_*1024 + vrow) * SQV + s_] =
                            sLDS[rowL*128 + ((((colL>>3) ^ (rowL&7)) << 3) | (colL & 7))];
                    }
                }
            }
        }
    }
}

// ----------------------------------------- f16 MFMA flash attention ---------
// q,k f16 row-major (NT x Dm); vt f16 transposed [(b*16+h)*64+d][SQV].
// 128-row q-tiles: each wave owns 32 q-rows (two 16-row groups) — halves K/V
// staging + barrier count per q-row vs the 64-row version and doubles MFMA
// per barrier pair. K/V register-prefetched one kt ahead (T14).
__global__ __launch_bounds__(256) void attn_mfma(
    const ush* __restrict__ q, const ush* __restrict__ k,
    const ush* __restrict__ vt, ush* __restrict__ cf)
{
    __shared__ ush sK[64*LDP], sVt[64*LDP];
    __shared__ ush sP[4][32*LDP];
    const int qt = blockIdx.x, h = blockIdx.y, b = blockIdx.z;
    const int t = threadIdx.x, lane = t & 63, w = t >> 6;
    const int quad = lane >> 4, l16 = lane & 15;
    const size_t base = (size_t)b * SQ * Dm + (size_t)h * HD;
    const size_t vbase = ((size_t)(b * 16 + h)) * 64 * SQV;
    const int q0 = qt * 128;

    // prefetch K/V tile 0 (loads in flight during Q staging)
    short8 kreg[2], vreg[2];
    auto prefetch = [&](int kt) {
        #pragma unroll
        for (int i = 0; i < 2; ++i) {
            const int u = t + i * 256;
            const int row = u >> 3, c8 = u & 7;
            const int s = kt * 64 + row;
            short8 kv = {0,0,0,0,0,0,0,0};
            if (s < SQ) kv = *(const short8*)(k + base + (size_t)s * Dm + c8 * 8);
            kreg[i] = kv;
            vreg[i] = *(const short8*)(vt + vbase + (size_t)row * SQV + kt*64 + c8*8);
        }
    };
    prefetch(0);

    // Q staging: two 64-row passes through sK; wave w reads its 32 rows
    half8 qf[2][2];
    #pragma unroll
    for (int p = 0; p < 2; ++p) {
        __syncthreads();
        #pragma unroll
        for (int i = 0; i < 2; ++i) {
            const int u = t + i * 256;
            const int row = u >> 3, c8 = u & 7;
            int s = q0 + p * 64 + row; if (s > SQ - 1) s = SQ - 1;
            *(short8*)&sK[row*LDP + c8*8] =
                *(const short8*)(q + base + (size_t)s * Dm + c8 * 8);
        }
        __syncthreads();
        if ((w >> 1) == p) {
            #pragma unroll
            for (int rg = 0; rg < 2; ++rg)
                #pragma unroll
                for (int s = 0; s < 2; ++s)
                    qf[rg][s] = *(const half8*)&sK[((w&1)*32 + rg*16 + l16)*LDP + s*32 + quad*8];
        }
    }

    floatx4 O[2][4] = {};
    float mrow[2][4], lrow[2][4];
    #pragma unroll
    for (int rg = 0; rg < 2; ++rg)
        #pragma unroll
        for (int r = 0; r < 4; ++r) { mrow[rg][r] = -1e30f; lrow[rg][r] = 0.f; }
    bool act[2];
    act[0] = (q0 + w * 32) < SQ;
    act[1] = (q0 + w * 32 + 16) < SQ;

    for (int kt = 0; kt < 5; ++kt) {
        __syncthreads();
        #pragma unroll
        for (int i = 0; i < 2; ++i) {
            const int u = t + i * 256;
            const int row = u >> 3, c8 = u & 7;
            *(short8*)&sK[row*LDP + c8*8] = kreg[i];
            *(short8*)&sVt[row*LDP + c8*8] = vreg[i];
        }
        if (kt < 4) prefetch(kt + 1);
        __syncthreads();
        if (!act[0]) continue;

        #pragma unroll
        for (int rg = 0; rg < 2; ++rg) {
            if (!act[rg]) continue;
            floatx4 S[4] = {};
            #pragma unroll
            for (int ni = 0; ni < 4; ++ni)
                #pragma unroll
                for (int s = 0; s < 2; ++s) {
                    half8 kf = *(const half8*)&sK[(ni*16 + l16)*LDP + s*32 + quad*8];
                    S[ni] = __builtin_amdgcn_mfma_f32_16x16x32_f16(qf[rg][s], kf, S[ni], 0, 0, 0);
                }
            #pragma unroll
            for (int ni = 0; ni < 4; ++ni) {
                const int jg = kt * 64 + ni * 16 + l16;
                if (jg >= SQ) { S[ni][0] = -1e30f; S[ni][1] = -1e30f; S[ni][2] = -1e30f; S[ni][3] = -1e30f; }
            }
            float mnew[4], alpha[4];
            #pragma unroll
            for (int r = 0; r < 4; ++r) {
                float mx = fmaxf(fmaxf(S[0][r], S[1][r]), fmaxf(S[2][r], S[3][r]));
                #pragma unroll
                for (int off = 1; off < 16; off <<= 1) mx = fmaxf(mx, __shfl_xor(mx, off, 64));
                mnew[r] = fmaxf(mrow[rg][r], mx);
                alpha[r] = __expf(mrow[rg][r] - mnew[r]);
                mrow[rg][r] = mnew[r];
            }
            float pe[4][4], rs[4];
            #pragma unroll
            for (int r = 0; r < 4; ++r) rs[r] = 0.f;
            #pragma unroll
            for (int ni = 0; ni < 4; ++ni)
                #pragma unroll
                for (int r = 0; r < 4; ++r) {
                    float e = __expf(S[ni][r] - mnew[r]);
                    pe[ni][r] = e; rs[r] += e;
                }
            #pragma unroll
            for (int r = 0; r < 4; ++r) {
                #pragma unroll
                for (int off = 1; off < 16; off <<= 1) rs[r] += __shfl_xor(rs[r], off, 64);
                lrow[rg][r] = lrow[rg][r] * alpha[r] + rs[r];
            }
            #pragma unroll
            for (int ni = 0; ni < 4; ++ni)
                #pragma unroll
                for (int r = 0; r < 4; ++r) O[rg][ni][r] *= alpha[r];
            #pragma unroll
            for (int ni = 0; ni < 4; ++ni)
                #pragma unroll
                for (int r = 0; r < 4; ++r)
                    sP[w][(rg*16 + quad*4 + r)*LDP + ni*16 + l16] = f2h(pe[ni][r]);
            #pragma unroll
            for (int ni = 0; ni < 4; ++ni)
                #pragma unroll
                for (int s = 0; s < 2; ++s) {
                    half8 a  = *(const half8*)&sP[w][(rg*16 + l16)*LDP + s*32 + quad*8];
                    half8 bb = *(const half8*)&sVt[(ni*16 + l16)*LDP + s*32 + quad*8];
                    O[rg][ni] = __builtin_amdgcn_mfma_f32_16x16x32_f16(a, bb, O[rg][ni], 0, 0, 0);
                }
        }
    }

    #pragma unroll
    for (int rg = 0; rg < 2; ++rg) {
        if (!act[rg]) continue;
        #pragma unroll
        for (int ni = 0; ni < 4; ++ni) {
            const int col = h * HD + ni * 16 + l16;
            #pragma unroll
            for (int r = 0; r < 4; ++r) {
                const int s = q0 + w * 32 + rg * 16 + quad * 4 + r;
                if (s < SQ)
                    cf[((size_t)(b * SQ + s)) * Dm + col] = f2h(O[rg][ni][r] / lrow[rg][r]);
            }
        }
    }
}

// ------------------------------------------------------------------ launch --
extern "C" void kernel_launch(void* const* d_in, const int* in_sizes, int n_in,
                              void* d_out, int out_size, void* d_ws, size_t ws_size,
                              hipStream_t stream)
{
    const float* x   = (const float*)d_in[0];
    const float* gw1 = (const float*)d_in[1];
    const float* gb1 = (const float*)d_in[2];
    const float* gw2 = (const float*)d_in[3];
    const float* gb2 = (const float*)d_in[4];
    const float *Wm[4], *U[4], *Sv[4], *Vv[4], *bias[4];
    for (int p = 0; p < 4; ++p) {
        Wm[p]   = (const float*)d_in[5 + p*5 + 0];
        U[p]    = (const float*)d_in[5 + p*5 + 1];
        Sv[p]   = (const float*)d_in[5 + p*5 + 2];
        Vv[p]   = (const float*)d_in[5 + p*5 + 3];
        bias[p] = (const float*)d_in[5 + p*5 + 4];
    }
    char* wsb   = (char*)d_ws;
    float* gates = (float*)wsb;           // 64 floats
    int*   idx   = (int*)(wsb + 256);     // 64 ints
    float* pool  = (float*)(wsb + 1024);  // 32*16*1024 floats = 2 MB
    ush* p = (ush*)(wsb + 1024 + (size_t)Bb * 16 * Dm * 4);
    ush* xf = p; p += (size_t)NT * Dm;
    ush* ef[4];
    for (int i = 0; i < 4; ++i) { ef[i] = p; p += (size_t)NT * 128; }
    ush* Bf[4];
    for (int i = 0; i < 4; ++i) { Bf[i] = p; p += (size_t)1024 * KX; }
    ush* Vf = p; p += (size_t)4 * Ee * Rr * Dm;
    ush* qf = p; p += (size_t)NT * Dm;
    ush* kf = p; p += (size_t)NT * Dm;
    ush* vt = p; p += (size_t)Bb * 16 * 64 * SQV;

    prep_kernel<<<5632, 256, 0, stream>>>(
        x, pool, xf,
        Wm[0], U[0], Wm[1], U[1], Wm[2], U[2], Wm[3], U[3],
        Vv[0], Vv[1], Vv[2], Vv[3],
        Bf[0], Bf[1], Bf[2], Bf[3], Vf);
    gating2_kernel<<<Bb, 256, 0, stream>>>(pool, gw1, gb1, gw2, gb2, gates, idx);

    ext_gemm<3><<<dim3(5, Bb, 2), 256, 0, stream>>>(xf, Vf,
        Sv[0], Sv[1], Sv[2], ef[0], ef[1], ef[2], gates, idx, 0);

    gemm_mfma<0><<<dim3(576, 1, 3), 256, 0, stream>>>(
        xf, ef[0], ef[1], ef[2], Bf[0], Bf[1], Bf[2],
        bias[0], bias[1], bias[2], qf, kf, vt, nullptr, 0.125f);

    // attention writes ctx f16 into xf (x no longer needed)
    attn_mfma<<<dim3(3, 16, Bb), 256, 0, stream>>>(qf, kf, vt, xf);

    ext_gemm<1><<<dim3(5, Bb, 2), 256, 0, stream>>>(xf, Vf,
        Sv[3], Sv[3], Sv[3], ef[3], ef[3], ef[3], gates, idx, 3);

    gemm_mfma<1><<<dim3(576, 1, 1), 256, 0, stream>>>(
        xf, ef[3], ef[3], ef[3], Bf[3], Bf[3], Bf[3],
        bias[3], bias[3], bias[3], nullptr, nullptr, nullptr, (float*)d_out, 1.0f);
}

// Round 9
// 349.167 us; speedup vs baseline: 1.1649x; 1.1649x over previous
//
#include <hip/hip_runtime.h>
#include <math.h>

#define Bb   32
#define SQ   257
#define SQV  320       // padded vt row stride (covers kt*64..+63 reads)
#define Dm   1024
#define HD   64
#define Ee   8
#define Rr   16
#define GHh  256
#define NT   (Bb*SQ)   // 8224
#define KX   1152      // 1024 + E*R extension
#define LDP  72        // padded LDS row (64 ush + 8) — attn only

typedef unsigned short ush;
typedef _Float16 h16;
typedef __attribute__((ext_vector_type(8))) _Float16 half8;
typedef __attribute__((ext_vector_type(4))) _Float16 half4;
typedef __attribute__((ext_vector_type(8))) short short8;
typedef __attribute__((ext_vector_type(4))) float floatx4;
typedef __attribute__((ext_vector_type(16))) float floatx16;

__device__ __forceinline__ ush f2h(float f) {
    union { h16 h; ush u; } a; a.h = (h16)f; return a.u;
}
__device__ __forceinline__ void store_h4(ush* p, float4 v) {
    half4 h; h.x = (h16)v.x; h.y = (h16)v.y; h.z = (h16)v.z; h.w = (h16)v.w;
    *(half4*)p = h;
}
__device__ __forceinline__ void load16(const ush* g, ush* l) {
    __builtin_amdgcn_global_load_lds(
        (const __attribute__((address_space(1))) unsigned int*)g,
        (__attribute__((address_space(3))) unsigned int*)l,
        16, 0, 0);
}

// ---------------- prep: pool+conv (blocks 0..511) | W/U/V conv (rest) -------
__global__ __launch_bounds__(256) void prep_kernel(
    const float* __restrict__ x, float* __restrict__ pp, ush* __restrict__ xf,
    const float* __restrict__ W0, const float* __restrict__ U0,
    const float* __restrict__ W1, const float* __restrict__ U1,
    const float* __restrict__ W2, const float* __restrict__ U2,
    const float* __restrict__ W3, const float* __restrict__ U3,
    const float* __restrict__ V0, const float* __restrict__ V1,
    const float* __restrict__ V2, const float* __restrict__ V3,
    ush* __restrict__ Bf0, ush* __restrict__ Bf1,
    ush* __restrict__ Bf2, ush* __restrict__ Bf3,
    ush* __restrict__ Vf)
{
    const int bid = blockIdx.x, t = threadIdx.x;
    if (bid < 512) {
        const int c = bid & 15, b = bid >> 4;
        const int s0 = c * 16, s1 = (c == 15) ? SQ : s0 + 16;
        float4 acc = make_float4(0.f, 0.f, 0.f, 0.f);
        const float* xp = x + ((size_t)b * SQ + s0) * Dm + t * 4;
        ush* xo = xf + ((size_t)b * SQ + s0) * Dm + t * 4;
        for (int s = s0; s < s1; ++s, xp += Dm, xo += Dm) {
            float4 v = *(const float4*)xp;
            store_h4(xo, v);
            acc.x += v.x; acc.y += v.y; acc.z += v.z; acc.w += v.w;
        }
        *(float4*)(pp + ((size_t)b * 16 + c) * Dm + t * 4) = acc;
        return;
    }
    const int bx = bid - 512;
    const int p = bx / 1280, xb = bx % 1280;
    if (xb < 1152) {
        const float* W = p == 0 ? W0 : p == 1 ? W1 : p == 2 ? W2 : W3;
        const float* U = p == 0 ? U0 : p == 1 ? U1 : p == 2 ? U2 : U3;
        ush* Bf = p == 0 ? Bf0 : p == 1 ? Bf1 : p == 2 ? Bf2 : Bf3;
        const int i = xb * 256 + t;
        const int n = i / 288, c4 = i % 288, col = c4 * 4;
        float4 v;
        if (col < Dm) {
            v = *(const float4*)(W + (size_t)n * Dm + col);
        } else {
            int ec = col - Dm, e = ec >> 4, r = ec & 15;
            v = *(const float4*)(U + ((size_t)(e * Dm + n)) * Rr + r);
        }
        store_h4(Bf + (size_t)n * KX + col, v);
    } else {
        const float* V = p == 0 ? V0 : p == 1 ? V1 : p == 2 ? V2 : V3;
        const size_t i = ((size_t)(xb - 1152) * 256 + t) * 4;
        float4 v = *(const float4*)(V + i);
        store_h4(Vf + (size_t)p * Ee * Rr * Dm + i, v);
    }
}

// --------------------- gating stage B1: hidden GEMV (4-way parallel) --------
// grid (Bb, 4): block computes 64 of the 256 hidden units for sample b.
__global__ __launch_bounds__(256) void gating_h(
    const float* __restrict__ pp, const float* __restrict__ gw1,
    const float* __restrict__ gb1, float* __restrict__ hbufg)
{
    __shared__ float pooled[Dm];
    const int b = blockIdx.x, slice = blockIdx.y, t = threadIdx.x;
    const int w = t >> 6, lane = t & 63;

    float4 acc = make_float4(0.f, 0.f, 0.f, 0.f);
    for (int c = 0; c < 16; ++c) {
        float4 v = *(const float4*)(pp + ((size_t)b * 16 + c) * Dm + t * 4);
        acc.x += v.x; acc.y += v.y; acc.z += v.z; acc.w += v.w;
    }
    const float sc = 1.0f / SQ;
    pooled[t*4+0] = acc.x * sc; pooled[t*4+1] = acc.y * sc;
    pooled[t*4+2] = acc.z * sc; pooled[t*4+3] = acc.w * sc;
    __syncthreads();

    for (int oi = 0; oi < 16; ++oi) {
        const int o = slice * 64 + w * 16 + oi;
        const float* g = gw1 + (size_t)o * Dm;
        float s = 0.f;
        #pragma unroll
        for (int i = 0; i < 16; ++i) s += pooled[lane + i*64] * g[lane + i*64];
        for (int off = 32; off > 0; off >>= 1) s += __shfl_down(s, off, 64);
        if (lane == 0) hbufg[b * GHh + o] = fmaxf(s + gb1[o], 0.f);
    }
}

// --------------------- gating stage B2: logits + top2 (tiny) ----------------
__global__ __launch_bounds__(64) void gating_top(
    const float* __restrict__ hbufg, const float* __restrict__ gw2,
    const float* __restrict__ gb2,
    float* __restrict__ gates, int* __restrict__ idx)
{
    __shared__ float logits[Ee];
    const int b = blockIdx.x, t = threadIdx.x;
    if (t < Ee) {
        const float* g = gw2 + t * GHh;
        const float* hb = hbufg + b * GHh;
        float s = 0.f;
        for (int j = 0; j < GHh; ++j) s += hb[j] * g[j];
        logits[t] = s + gb2[t];
    }
    __syncthreads();
    if (t == 0) {
        int i1 = 0; float v1 = logits[0];
        for (int e = 1; e < Ee; ++e) if (logits[e] > v1) { v1 = logits[e]; i1 = e; }
        int i2 = 0; float v2 = -1e30f;
        for (int e = 0; e < Ee; ++e) if (e != i1 && logits[e] > v2) { v2 = logits[e]; i2 = e; }
        float e2 = __expf(v2 - v1);
        float inv = 1.f / (1.f + e2);
        gates[b*2+0] = inv; gates[b*2+1] = e2 * inv;
        idx[b*2+0] = i1; idx[b*2+1] = i2;
    }
}

// --------------- ext as MFMA GEMM: xvs[s,j] = gS * (x[s,:] . Vsel[j,:]) -----
// grid (5 m-tiles, Bb, 2 experts). BK=64. kk==0 blocks zero the 6 non-selected
// expert slices (replaces the old zero_kernel launch).
template<int NP>
__global__ __launch_bounds__(256) void ext_gemm(
    const ush* __restrict__ xf,
    const ush* __restrict__ Vf,                               // [4][128][1024]
    const float* __restrict__ S0, const float* __restrict__ S1,
    const float* __restrict__ S2,
    ush* __restrict__ o0, ush* __restrict__ o1, ush* __restrict__ o2,
    const float* __restrict__ gates, const int* __restrict__ idx, int pbase)
{
    __shared__ ush sA[2*64*32], sB[2*NP*16*32];
    const int mt = blockIdx.x, b = blockIdx.y, kk = blockIdx.z;
    const int t = threadIdx.x, lane = t & 63, w = t >> 6;
    const int quad = lane >> 4, l16 = lane & 15;
    const int s0 = mt * 64;
    const int e = idx[b*2+kk];
    const float g = gates[b*2+kk];

    if (kk == 0) {
        const int e0 = idx[b*2+0], e1 = idx[b*2+1];
        int zexp[6]; int nz = 0;
        #pragma unroll
        for (int ez = 0; ez < Ee; ++ez)
            if (ez != e0 && ez != e1) zexp[nz++] = ez;
        short8 zv = {0,0,0,0,0,0,0,0};
        for (int u = t; u < NP*64*6; u += 256) {
            const int ei = u % 6; int rest = u / 6;
            const int r64 = rest & 63; const int p = rest >> 6;
            const int s = s0 + r64;
            if (s < SQ) {
                ush* oo = p == 0 ? o0 : p == 1 ? o1 : o2;
                ush* dst = oo + ((size_t)(b*SQ + s)) * 128 + zexp[ei]*16;
                *(short8*)dst = zv;
                *(short8*)(dst + 8) = zv;
            }
        }
    }

    const int rl = lane >> 2;
    const int swsrc = ((lane & 3) ^ ((lane >> 3) & 3)) * 8;  // staging chunk
    const int swrd  = ((quad ^ ((l16 >> 1) & 3)) * 8);       // read chunk

    int sa = s0 + w * 16 + rl; if (sa > SQ - 1) sa = SQ - 1;
    const ush* aptr = xf + ((size_t)(b * SQ + sa)) * Dm + swsrc;
    const ush* bptr = (w < NP)
        ? Vf + ((size_t)(pbase + w)) * Ee * Rr * Dm + ((size_t)(e * Rr + rl)) * Dm + swsrc
        : nullptr;
    ush* la0 = &sA[w * 512];
    ush* la1 = &sA[2048 + w * 512];
    ush* lb0 = (w < NP) ? &sB[w * 512] : nullptr;
    ush* lb1 = (w < NP) ? &sB[NP*512 + w * 512] : nullptr;

    floatx4 S[NP] = {};

    for (int it = 0; it < 16; ++it) {
        __syncthreads();
        load16(aptr, la0); load16(aptr + 32, la1); aptr += 64;
        if (w < NP) {
            load16(bptr, lb0); load16(bptr + 32, lb1); bptr += 64;
        }
        __syncthreads();
        #pragma unroll
        for (int j = 0; j < 2; ++j) {
            const half8 a = *(const half8*)&sA[j*2048 + (w*16 + l16)*32 + swrd];
            #pragma unroll
            for (int p = 0; p < NP; ++p) {
                const half8 bb = *(const half8*)&sB[j*NP*512 + (p*16 + l16)*32 + swrd];
                S[p] = __builtin_amdgcn_mfma_f32_16x16x32_f16(a, bb, S[p], 0, 0, 0);
            }
        }
    }

    #pragma unroll
    for (int p = 0; p < NP; ++p) {
        const float* Sp = p == 0 ? S0 : p == 1 ? S1 : S2;
        const float scale = g * Sp[e * Rr + l16];
        ush* oo = p == 0 ? o0 : p == 1 ? o1 : o2;
        #pragma unroll
        for (int r = 0; r < 4; ++r) {
            const int s = s0 + w * 16 + quad * 4 + r;
            if (s < SQ)
                oo[((size_t)(b * SQ + s)) * 128 + e * 16 + l16] = f2h(S[p][r] * scale);
        }
    }
}

// ------------- f16 MFMA GEMM (32x32x16), K=1152 (1024+ext), BK=64 -----------
template<int MODE>
__global__ __launch_bounds__(256) void gemm_mfma(
    const ush* __restrict__ A,
    const ush* __restrict__ E0, const ush* __restrict__ E1, const ush* __restrict__ E2,
    const ush* __restrict__ B0, const ush* __restrict__ B1, const ush* __restrict__ B2,
    const float* __restrict__ b0, const float* __restrict__ b1, const float* __restrict__ b2,
    ush* __restrict__ y0, ush* __restrict__ y1, ush* __restrict__ vt,
    float* __restrict__ yo, float qscale)
{
    const int stripe = blockIdx.x % 72;
    if (stripe >= 65) return;
    const int nb = blockIdx.x / 72;
    const int z = blockIdx.z;
    const ush* E = z == 0 ? E0 : z == 1 ? E1 : E2;
    const ush* Bm = z == 0 ? B0 : z == 1 ? B1 : B2;
    const float* bias = z == 0 ? b0 : z == 1 ? b1 : b2;

    __shared__ ush sLDS[2*128*64];      // sA | sB ; reused as C-repack (128x128)
    ush* sA = sLDS;
    ush* sB = sLDS + 128*64;
    const int t = threadIdx.x, lane = t & 63, w = t >> 6;
    const int m0 = stripe * 128, n0 = nb * 128;
    const int row8 = lane >> 3, c8l = lane & 7;
    const int swk = (c8l ^ row8) * 8;
    const int wm = w >> 1, wn = w & 1;
    const int l31 = lane & 31, h5 = lane >> 5;

    const ush* ap[4]; const ush* ep[4]; const ush* bp[4];
    ush *la[4], *lb[4];
    #pragma unroll
    for (int c = 0; c < 4; ++c) {
        const int j = c * 4 + w;
        const int rowl = j * 8 + row8;
        int rga = m0 + rowl; if (rga > NT - 1) rga = NT - 1;
        ap[c] = A + (size_t)rga * Dm + swk;
        ep[c] = E + (size_t)rga * 128 + swk;
        bp[c] = Bm + (size_t)(n0 + rowl) * KX + swk;
        la[c] = &sA[j * 512];
        lb[c] = &sB[j * 512];
    }

    int aofs[4][2], bofs[4][2];
    #pragma unroll
    for (int s = 0; s < 4; ++s)
        #pragma unroll
        for (int i = 0; i < 2; ++i) {
            const int g = s * 2 + h5;
            aofs[s][i] = (wm*64 + i*32 + l31) * 64 + ((g ^ (l31 & 7)) * 8);
            bofs[s][i] = (wn*64 + i*32 + l31) * 64 + ((g ^ (l31 & 7)) * 8);
        }

    floatx16 acc[2][2] = {};

    for (int it = 0; it < 16; ++it) {       // main K: xf columns 0..1023
        __syncthreads();
        #pragma unroll
        for (int c = 0; c < 4; ++c) {
            load16(ap[c], la[c]); ap[c] += 64;
            load16(bp[c], lb[c]); bp[c] += 64;
        }
        __syncthreads();
        #pragma unroll
        for (int s = 0; s < 4; ++s) {
            half8 af0 = *(const half8*)&sA[aofs[s][0]];
            half8 af1 = *(const half8*)&sA[aofs[s][1]];
            half8 bf0 = *(const half8*)&sB[bofs[s][0]];
            half8 bf1 = *(const half8*)&sB[bofs[s][1]];
            acc[0][0] = __builtin_amdgcn_mfma_f32_32x32x16_f16(af0, bf0, acc[0][0], 0, 0, 0);
            acc[0][1] = __builtin_amdgcn_mfma_f32_32x32x16_f16(af0, bf1, acc[0][1], 0, 0, 0);
            acc[1][0] = __builtin_amdgcn_mfma_f32_32x32x16_f16(af1, bf0, acc[1][0], 0, 0, 0);
            acc[1][1] = __builtin_amdgcn_mfma_f32_32x32x16_f16(af1, bf1, acc[1][1], 0, 0, 0);
        }
    }
    for (int it = 0; it < 2; ++it) {        // ext K: E columns 0..127
        __syncthreads();
        #pragma unroll
        for (int c = 0; c < 4; ++c) {
            load16(ep[c], la[c]); ep[c] += 64;
            load16(bp[c], lb[c]); bp[c] += 64;
        }
        __syncthreads();
        #pragma unroll
        for (int s = 0; s < 4; ++s) {
            half8 af0 = *(const half8*)&sA[aofs[s][0]];
            half8 af1 = *(const half8*)&sA[aofs[s][1]];
            half8 bf0 = *(const half8*)&sB[bofs[s][0]];
            half8 bf1 = *(const half8*)&sB[bofs[s][1]];
            acc[0][0] = __builtin_amdgcn_mfma_f32_32x32x16_f16(af0, bf0, acc[0][0], 0, 0, 0);
            acc[0][1] = __builtin_amdgcn_mfma_f32_32x32x16_f16(af0, bf1, acc[0][1], 0, 0, 0);
            acc[1][0] = __builtin_amdgcn_mfma_f32_32x32x16_f16(af1, bf0, acc[1][0], 0, 0, 0);
            acc[1][1] = __builtin_amdgcn_mfma_f32_32x32x16_f16(af1, bf1, acc[1][1], 0, 0, 0);
        }
    }

    // ---- epilogue: 32x32 C layout: col=lane&31, row=(r&3)+8*(r>>2)+4*(lane>>5)
    if (MODE == 1) {
        #pragma unroll
        for (int mi = 0; mi < 2; ++mi) {
            #pragma unroll
            for (int ni = 0; ni < 2; ++ni) {
                const int col = n0 + wn*64 + ni*32 + l31;
                const float bsv = bias[col];
                const int rb = m0 + wm*64 + mi*32 + 4*h5;
                #pragma unroll
                for (int r = 0; r < 16; ++r) {
                    const int row = rb + (r & 3) + 8 * (r >> 2);
                    if (row < NT)
                        yo[(size_t)row * Dm + col] = acc[mi][ni][r] + bsv;
                }
            }
        }
    } else {
        __syncthreads();     // all waves done with sA/sB reads
        #pragma unroll
        for (int mi = 0; mi < 2; ++mi) {
            #pragma unroll
            for (int ni = 0; ni < 2; ++ni) {
                const int colL = wn*64 + ni*32 + l31;
                const float bsv = bias[n0 + colL];
                const int rbL = wm*64 + mi*32 + 4*h5;
                #pragma unroll
                for (int r = 0; r < 16; ++r) {
                    const int rowL = rbL + (r & 3) + 8 * (r >> 2);
                    float val = acc[mi][ni][r] + bsv;
                    if (z == 0) val *= qscale;
                    sLDS[rowL*128 + ((((colL>>3) ^ (rowL&7)) << 3) | (colL & 7))] = f2h(val);
                }
            }
        }
        __syncthreads();
        if (z != 2) {
            ush* y = (z == 0) ? y0 : y1;
            #pragma unroll
            for (int i = 0; i < 8; ++i) {
                const int u = i*256 + t;
                const int rowL = u >> 4, cj = u & 15;
                const int row = m0 + rowL;
                if (row < NT) {
                    half8 v = *(const half8*)&sLDS[rowL*128 + ((cj ^ (rowL&7)) << 3)];
                    *(half8*)(y + (size_t)row * Dm + n0 + cj*8) = v;
                }
            }
        } else {
            #pragma unroll
            for (int i = 0; i < 8; ++i) {
                const int u = i*256 + t;
                const int oct = u & 15, colL = u >> 4;
                const int colg = n0 + colL;
                const int h_ = colg >> 6, d_ = colg & 63;
                const size_t vrow = (size_t)h_ * 64 + d_;
                #pragma unroll
                for (int jj = 0; jj < 8; ++jj) {
                    const int rowL = oct + jj*16;
                    const int row = m0 + rowL;
                    if (row < NT) {
                        const int b_ = row / SQ, s_ = row - b_*SQ;
                        vt[((size_t)b_*1024 + vrow) * SQV + s_] =
                            sLDS[rowL*128 + ((((colL>>3) ^ (rowL&7)) << 3) | (colL & 7))];
                    }
                }
            }
        }
    }
}

// ----------------------------------------- f16 MFMA flash attention ---------
// q,k f16 row-major (NT x Dm); vt f16 transposed [(b*16+h)*64+d][SQV].
// 64-row q-tiles (round-7 form: best measured); K/V register-prefetched one
// kt ahead (T14) so HBM/L2 latency hides under the previous tile's compute.
__global__ __launch_bounds__(256) void attn_mfma(
    const ush* __restrict__ q, const ush* __restrict__ k,
    const ush* __restrict__ vt, ush* __restrict__ cf)
{
    __shared__ ush sK[64*LDP], sVt[64*LDP];
    __shared__ ush sP[4][16*LDP];
    const int qt = blockIdx.x, h = blockIdx.y, b = blockIdx.z;
    const int t = threadIdx.x, lane = t & 63, w = t >> 6;
    const int quad = lane >> 4, l16 = lane & 15;
    const size_t base = (size_t)b * SQ * Dm + (size_t)h * HD;
    const size_t vbase = ((size_t)(b * 16 + h)) * 64 * SQV;

    #pragma unroll
    for (int i = 0; i < 2; ++i) {
        const int u = t + i * 256;
        const int row = u >> 3, c8 = u & 7;
        int s = qt * 64 + row; if (s > SQ - 1) s = SQ - 1;
        short8 ld = *(const short8*)(q + base + (size_t)s * Dm + c8 * 8);
        *(short8*)&sK[row*LDP + c8*8] = ld;
    }
    __syncthreads();
    half8 qf[2];
    #pragma unroll
    for (int s = 0; s < 2; ++s)
        qf[s] = *(const half8*)&sK[(w*16 + l16)*LDP + s*32 + quad*8];

    floatx4 O[4] = {};
    float mrow[4], lrow[4];
    #pragma unroll
    for (int r = 0; r < 4; ++r) { mrow[r] = -1e30f; lrow[r] = 0.f; }
    const bool active = (qt * 64 + w * 16) < SQ;

    short8 kreg[2], vreg[2];
    auto prefetch = [&](int kt) {
        #pragma unroll
        for (int i = 0; i < 2; ++i) {
            const int u = t + i * 256;
            const int row = u >> 3, c8 = u & 7;
            const int s = kt * 64 + row;
            short8 kv = {0,0,0,0,0,0,0,0};
            if (s < SQ) kv = *(const short8*)(k + base + (size_t)s * Dm + c8 * 8);
            kreg[i] = kv;
            vreg[i] = *(const short8*)(vt + vbase + (size_t)row * SQV + kt*64 + c8*8);
        }
    };
    prefetch(0);

    for (int kt = 0; kt < 5; ++kt) {
        __syncthreads();
        #pragma unroll
        for (int i = 0; i < 2; ++i) {
            const int u = t + i * 256;
            const int row = u >> 3, c8 = u & 7;
            *(short8*)&sK[row*LDP + c8*8] = kreg[i];
            *(short8*)&sVt[row*LDP + c8*8] = vreg[i];
        }
        if (kt < 4) prefetch(kt + 1);
        __syncthreads();
        if (!active) continue;

        floatx4 S[4] = {};
        #pragma unroll
        for (int ni = 0; ni < 4; ++ni)
            #pragma unroll
            for (int s = 0; s < 2; ++s) {
                half8 kf = *(const half8*)&sK[(ni*16 + l16)*LDP + s*32 + quad*8];
                S[ni] = __builtin_amdgcn_mfma_f32_16x16x32_f16(qf[s], kf, S[ni], 0, 0, 0);
            }
        #pragma unroll
        for (int ni = 0; ni < 4; ++ni) {
            const int jg = kt * 64 + ni * 16 + l16;
            if (jg >= SQ) { S[ni][0] = -1e30f; S[ni][1] = -1e30f; S[ni][2] = -1e30f; S[ni][3] = -1e30f; }
        }
        float mnew[4], alpha[4];
        #pragma unroll
        for (int r = 0; r < 4; ++r) {
            float mx = fmaxf(fmaxf(S[0][r], S[1][r]), fmaxf(S[2][r], S[3][r]));
            #pragma unroll
            for (int off = 1; off < 16; off <<= 1) mx = fmaxf(mx, __shfl_xor(mx, off, 64));
            mnew[r] = fmaxf(mrow[r], mx);
            alpha[r] = __expf(mrow[r] - mnew[r]);
            mrow[r] = mnew[r];
        }
        float p[4][4], rs[4];
        #pragma unroll
        for (int r = 0; r < 4; ++r) rs[r] = 0.f;
        #pragma unroll
        for (int ni = 0; ni < 4; ++ni)
            #pragma unroll
            for (int r = 0; r < 4; ++r) {
                float e = __expf(S[ni][r] - mnew[r]);
                p[ni][r] = e; rs[r] += e;
            }
        #pragma unroll
        for (int r = 0; r < 4; ++r) {
            #pragma unroll
            for (int off = 1; off < 16; off <<= 1) rs[r] += __shfl_xor(rs[r], off, 64);
            lrow[r] = lrow[r] * alpha[r] + rs[r];
        }
        #pragma unroll
        for (int ni = 0; ni < 4; ++ni)
            #pragma unroll
            for (int r = 0; r < 4; ++r) O[ni][r] *= alpha[r];
        #pragma unroll
        for (int ni = 0; ni < 4; ++ni)
            #pragma unroll
            for (int r = 0; r < 4; ++r)
                sP[w][(quad*4 + r)*LDP + ni*16 + l16] = f2h(p[ni][r]);
        #pragma unroll
        for (int ni = 0; ni < 4; ++ni)
            #pragma unroll
            for (int s = 0; s < 2; ++s) {
                half8 a  = *(const half8*)&sP[w][l16*LDP + s*32 + quad*8];
                half8 bb = *(const half8*)&sVt[(ni*16 + l16)*LDP + s*32 + quad*8];
                O[ni] = __builtin_amdgcn_mfma_f32_16x16x32_f16(a, bb, O[ni], 0, 0, 0);
            }
    }

    if (active) {
        #pragma unroll
        for (int ni = 0; ni < 4; ++ni) {
            const int col = h * HD + ni * 16 + l16;
            #pragma unroll
            for (int r = 0; r < 4; ++r) {
                const int s = qt * 64 + w * 16 + quad * 4 + r;
                if (s < SQ)
                    cf[((size_t)(b * SQ + s)) * Dm + col] = f2h(O[ni][r] / lrow[r]);
            }
        }
    }
}

// ------------------------------------------------------------------ launch --
extern "C" void kernel_launch(void* const* d_in, const int* in_sizes, int n_in,
                              void* d_out, int out_size, void* d_ws, size_t ws_size,
                              hipStream_t stream)
{
    const float* x   = (const float*)d_in[0];
    const float* gw1 = (const float*)d_in[1];
    const float* gb1 = (const float*)d_in[2];
    const float* gw2 = (const float*)d_in[3];
    const float* gb2 = (const float*)d_in[4];
    const float *Wm[4], *U[4], *Sv[4], *Vv[4], *bias[4];
    for (int p = 0; p < 4; ++p) {
        Wm[p]   = (const float*)d_in[5 + p*5 + 0];
        U[p]    = (const float*)d_in[5 + p*5 + 1];
        Sv[p]   = (const float*)d_in[5 + p*5 + 2];
        Vv[p]   = (const float*)d_in[5 + p*5 + 3];
        bias[p] = (const float*)d_in[5 + p*5 + 4];
    }
    char* wsb   = (char*)d_ws;
    float* gates = (float*)wsb;           // 64 floats
    int*   idx   = (int*)(wsb + 256);     // 64 ints
    float* pool  = (float*)(wsb + 1024);  // 32*16*1024 floats = 2 MB
    float* hbufg = (float*)(wsb + 1024 + (size_t)Bb * 16 * Dm * 4);  // 32*256 f
    ush* p = (ush*)(wsb + 1024 + (size_t)Bb * 16 * Dm * 4 + (size_t)Bb * GHh * 4);
    ush* xf = p; p += (size_t)NT * Dm;
    ush* ef[4];
    for (int i = 0; i < 4; ++i) { ef[i] = p; p += (size_t)NT * 128; }
    ush* Bf[4];
    for (int i = 0; i < 4; ++i) { Bf[i] = p; p += (size_t)1024 * KX; }
    ush* Vf = p; p += (size_t)4 * Ee * Rr * Dm;
    ush* qf = p; p += (size_t)NT * Dm;
    ush* kf = p; p += (size_t)NT * Dm;
    ush* vt = p; p += (size_t)Bb * 16 * 64 * SQV;

    prep_kernel<<<5632, 256, 0, stream>>>(
        x, pool, xf,
        Wm[0], U[0], Wm[1], U[1], Wm[2], U[2], Wm[3], U[3],
        Vv[0], Vv[1], Vv[2], Vv[3],
        Bf[0], Bf[1], Bf[2], Bf[3], Vf);
    gating_h<<<dim3(Bb, 4), 256, 0, stream>>>(pool, gw1, gb1, hbufg);
    gating_top<<<Bb, 64, 0, stream>>>(hbufg, gw2, gb2, gates, idx);

    ext_gemm<3><<<dim3(5, Bb, 2), 256, 0, stream>>>(xf, Vf,
        Sv[0], Sv[1], Sv[2], ef[0], ef[1], ef[2], gates, idx, 0);

    gemm_mfma<0><<<dim3(576, 1, 3), 256, 0, stream>>>(
        xf, ef[0], ef[1], ef[2], Bf[0], Bf[1], Bf[2],
        bias[0], bias[1], bias[2], qf, kf, vt, nullptr, 0.125f);

    // attention writes ctx f16 into xf (x no longer needed)
    attn_mfma<<<dim3(5, 16, Bb), 256, 0, stream>>>(qf, kf, vt, xf);

    ext_gemm<1><<<dim3(5, Bb, 2), 256, 0, stream>>>(xf, Vf,
        Sv[3], Sv[3], Sv[3], ef[3], ef[3], ef[3], gates, idx, 3);

    gemm_mfma<1><<<dim3(576, 1, 1), 256, 0, stream>>>(
        xf, ef[3], ef[3], ef[3], Bf[3], Bf[3], Bf[3],
        bias[3], bias[3], bias[3], nullptr, nullptr, nullptr, (float*)d_out, 1.0f);
}